// Round 1
// baseline (733.291 us; speedup 1.0000x reference)
//
#include <hip/hip_runtime.h>
#include <math.h>

#define B 32
#define C 256
#define CS 64
#define HW 12544          // 112*112
#define HW4 3136          // HW/4
#define NPLANES (B * C)   // 8192
#define N4 (NPLANES * HW4) // 25,690,112 float4s

// ---------------- Kernel 1: per-plane sum (global average pool numerator) ---
__global__ __launch_bounds__(256) void pool_kernel(const float* __restrict__ x,
                                                   float* __restrict__ sums) {
    const int plane = blockIdx.x;                 // 0 .. 8191
    const float4* p = (const float4*)(x + (size_t)plane * HW);
    float acc = 0.0f;
    for (int i = threadIdx.x; i < HW4; i += 256) {
        float4 v = p[i];
        acc += (v.x + v.y) + (v.z + v.w);
    }
    // wave (64-lane) shuffle reduction
    for (int off = 32; off > 0; off >>= 1)
        acc += __shfl_down(acc, off, 64);
    __shared__ float ws[4];
    const int lane = threadIdx.x & 63;
    const int wid  = threadIdx.x >> 6;
    if (lane == 0) ws[wid] = acc;
    __syncthreads();
    if (threadIdx.x == 0)
        sums[plane] = (ws[0] + ws[1]) + (ws[2] + ws[3]);
}

// ---------------- Kernel 2: SE MLP (reduce->swish->expand->sigmoid) --------
__global__ __launch_bounds__(256) void se_mlp_kernel(const float* __restrict__ sums,
                                                     const float* __restrict__ w_reduce,
                                                     const float* __restrict__ b_reduce,
                                                     const float* __restrict__ w_expand,
                                                     const float* __restrict__ b_expand,
                                                     float* __restrict__ gates) {
    __shared__ float ys[C];
    __shared__ float hs[CS];
    const int b = blockIdx.x;     // 0..31
    const int t = threadIdx.x;    // 0..255

    ys[t] = sums[b * C + t] * (1.0f / (float)HW);  // mean
    __syncthreads();

    if (t < CS) {
        float acc = b_reduce[t];
        const float* wr = w_reduce + t * C;
        #pragma unroll 8
        for (int c = 0; c < C; ++c) acc += ys[c] * wr[c];
        float s = 1.0f / (1.0f + __expf(-acc));
        hs[t] = acc * s;          // swish
    }
    __syncthreads();

    float acc = b_expand[t];
    const float* we = w_expand + t * CS;
    #pragma unroll 8
    for (int s = 0; s < CS; ++s) acc += hs[s] * we[s];
    gates[b * C + t] = 1.0f / (1.0f + __expf(-acc));  // sigmoid gate
}

// ---------------- Kernel 3: broadcast multiply -----------------------------
__global__ __launch_bounds__(256) void scale_kernel(const float* __restrict__ x,
                                                    const float* __restrict__ gates,
                                                    float* __restrict__ out) {
    const int idx = blockIdx.x * 256 + threadIdx.x;   // one float4 per thread
    if (idx >= N4) return;
    const int plane = idx / HW4;                      // (b*C + c)
    const float g = gates[plane];
    float4 v = ((const float4*)x)[idx];
    v.x *= g; v.y *= g; v.z *= g; v.w *= g;
    ((float4*)out)[idx] = v;
}

extern "C" void kernel_launch(void* const* d_in, const int* in_sizes, int n_in,
                              void* d_out, int out_size, void* d_ws, size_t ws_size,
                              hipStream_t stream) {
    const float* x        = (const float*)d_in[0];
    const float* w_reduce = (const float*)d_in[1];
    const float* b_reduce = (const float*)d_in[2];
    const float* w_expand = (const float*)d_in[3];
    const float* b_expand = (const float*)d_in[4];
    float* out = (float*)d_out;

    float* sums  = (float*)d_ws;          // NPLANES floats
    float* gates = sums + NPLANES;        // NPLANES floats

    pool_kernel<<<NPLANES, 256, 0, stream>>>(x, sums);
    se_mlp_kernel<<<B, 256, 0, stream>>>(sums, w_reduce, b_reduce,
                                         w_expand, b_expand, gates);
    const int nblocks = (N4 + 255) / 256;  // 100352
    scale_kernel<<<nblocks, 256, 0, stream>>>(x, gates, out);
}